// Round 8
// baseline (190.359 us; speedup 1.0000x reference)
//
#include <hip/hip_runtime.h>
#include <cstddef>

#define D_MODEL 1024
#define DK 64
#define NH 16
#define NB 2
#define SEQ 2048

typedef __attribute__((ext_vector_type(8))) short bf16x8;
typedef __attribute__((ext_vector_type(4))) float floatx4;
typedef __attribute__((ext_vector_type(2))) unsigned uintx2;

static __device__ __forceinline__ unsigned short f2bf(float f) {
    union { float f; unsigned u; } v; v.f = f;
    unsigned r = (v.u + 0x7fffu + ((v.u >> 16) & 1u)) >> 16;
    return (unsigned short)r;
}

// pack two floats' bf16 (round-half-away) into one dword
static __device__ __forceinline__ unsigned pk2bf(float lo, float hi) {
    unsigned ua = __float_as_uint(lo) + 0x8000u;
    unsigned ub = __float_as_uint(hi) + 0x8000u;
    return __builtin_amdgcn_perm(ub, ua, 0x07060302u);
}

static __device__ __forceinline__ void gld16(const unsigned short* g, unsigned short* l) {
    __builtin_amdgcn_global_load_lds(
        (const __attribute__((address_space(1))) unsigned int*)g,
        (__attribute__((address_space(3))) unsigned int*)l, 16, 0, 0);
}

// ---------------------------------------------------------------------------
// prep: fused convert_x (blocks 0..1023) + pack_w (blocks 1024..2047).
// ---------------------------------------------------------------------------
__global__ __launch_bounds__(256) void prep(
    const float* __restrict__ x, unsigned short* __restrict__ xb,
    const float* __restrict__ Wq, const float* __restrict__ Wk,
    const float* __restrict__ Wv, const float* __restrict__ Wo,
    unsigned short* __restrict__ Bqkv, unsigned short* __restrict__ Bo)
{
    __shared__ float T[64][65];
    const int tid = threadIdx.x;

    if (blockIdx.x < 1024) {
        const size_t i = ((size_t)blockIdx.x * 256 + tid) * 16;
#pragma unroll
        for (int c = 0; c < 16; c += 4) {
            float4 v = *(const float4*)&x[i + c];
            uint2 pk;
            pk.x = (unsigned)f2bf(v.x) | ((unsigned)f2bf(v.y) << 16);
            pk.y = (unsigned)f2bf(v.z) | ((unsigned)f2bf(v.w) << 16);
            *(uint2*)&xb[i + c] = pk;
        }
        return;
    }

    const int t   = blockIdx.x - 1024;
    const int rr   = tid >> 2;
    const int cseg = (tid & 3) * 16;

    const float* src;
    unsigned short* dst;
    if (t < 768) {
        const int proj = t / 256, rem = t % 256;
        const int h = rem >> 4, d0 = (rem & 15) * 64;
        const float* W = proj == 0 ? Wq : (proj == 1 ? Wk : Wv);
        src = W + ((size_t)h * 1024 + d0) * 64;
#pragma unroll
        for (int c = 0; c < 16; c += 4) {
            float4 v = *(const float4*)&src[(size_t)rr * 64 + cseg + c];
            T[rr][cseg + c + 0] = v.x; T[rr][cseg + c + 1] = v.y;
            T[rr][cseg + c + 2] = v.z; T[rr][cseg + c + 3] = v.w;
        }
        __syncthreads();
        dst = &Bqkv[((size_t)proj * 1024 + h * 64 + rr) * 1024 + d0 + cseg];
    } else {
        const int t2 = t - 768;
        const int k0 = (t2 >> 4) * 64, nb0 = (t2 & 15) * 64;
#pragma unroll
        for (int c = 0; c < 16; c += 4) {
            float4 v = *(const float4*)&Wo[(size_t)(k0 + rr) * 1024 + nb0 + cseg + c];
            T[rr][cseg + c + 0] = v.x; T[rr][cseg + c + 1] = v.y;
            T[rr][cseg + c + 2] = v.z; T[rr][cseg + c + 3] = v.w;
        }
        __syncthreads();
        dst = &Bo[(size_t)(nb0 + rr) * 1024 + k0 + cseg];
    }
    unsigned int w[8];
#pragma unroll
    for (int ii = 0; ii < 8; ii++) {
        unsigned short lo = f2bf(T[cseg + ii * 2 + 0][rr]);
        unsigned short hi = f2bf(T[cseg + ii * 2 + 1][rr]);
        w[ii] = (unsigned)lo | ((unsigned)hi << 16);
    }
    *(uint4*)(dst + 0) = make_uint4(w[0], w[1], w[2], w[3]);
    *(uint4*)(dst + 8) = make_uint4(w[4], w[5], w[6], w[7]);
}

// ---------------------------------------------------------------------------
// gemm_qkv (R14/BK=32, unchanged)
// ---------------------------------------------------------------------------
__global__ __launch_bounds__(256) void gemm_qkv(
    const unsigned short* __restrict__ Abf,
    const unsigned short* __restrict__ Bp,
    const float* __restrict__ bq, const float* __restrict__ bk,
    const float* __restrict__ bv,
    unsigned short* __restrict__ Qo, unsigned short* __restrict__ Ko,
    unsigned short* __restrict__ Vo)
{
    __shared__ __align__(16) unsigned short As[128 * 32];
    __shared__ __align__(16) unsigned short Bs[128 * 32];

    const int tid  = threadIdx.x;
    const int wv   = tid >> 6, lane = tid & 63;
    const int m0   = blockIdx.x * 128;
    const int n0   = blockIdx.y * 128;
    const int lq   = lane & 15, g = lane >> 4;
    const int wm   = (wv >> 1) * 64;
    const int wn   = (wv & 1) * 64;
    const int srow = lane >> 2;
    const int sseg = (lane & 3) * 8;

    floatx4 acc[4][4];
#pragma unroll
    for (int i = 0; i < 4; i++)
#pragma unroll
        for (int j = 0; j < 4; j++) acc[i][j] = (floatx4){0.f, 0.f, 0.f, 0.f};

    for (int k0 = 0; k0 < 1024; k0 += 32) {
#pragma unroll
        for (int r = 0; r < 2; r++) {
            const int chunk = wv * 2 + r;
            const int row   = chunk * 16 + srow;
            gld16(&Abf[(size_t)(m0 + row) * 1024 + k0 + sseg], &As[chunk * 512]);
            gld16(&Bp [(size_t)(n0 + row) * 1024 + k0 + sseg], &Bs[chunk * 512]);
        }
        __syncthreads();
        bf16x8 af[4], bfv[4];
#pragma unroll
        for (int i = 0; i < 4; i++)
            af[i] = *(const bf16x8*)&As[(wm + i * 16 + lq) * 32 + g * 8];
#pragma unroll
        for (int j = 0; j < 4; j++)
            bfv[j] = *(const bf16x8*)&Bs[(wn + j * 16 + lq) * 32 + g * 8];
#pragma unroll
        for (int i = 0; i < 4; i++)
#pragma unroll
            for (int j = 0; j < 4; j++)
                acc[i][j] = __builtin_amdgcn_mfma_f32_16x16x32_bf16(af[i], bfv[j], acc[i][j], 0, 0, 0);
        __syncthreads();
    }

    const int proj = n0 >> 10;
    const float* bias = proj == 0 ? bq : (proj == 1 ? bk : bv);
    unsigned short* OutQK = proj == 0 ? Qo : Ko;

#pragma unroll
    for (int j = 0; j < 4; j++) {
        const int n  = n0 + wn + j * 16 + lq;
        const int nn = n & 1023;
        const int h  = nn >> 6, dk = nn & 63;
        const float bb = bias[nn];
#pragma unroll
        for (int i = 0; i < 4; i++) {
            const int mbase = m0 + wm + i * 16 + g * 4;
            const int b_ = mbase >> 11;
            const int s_ = mbase & (SEQ - 1);
            const int bh = b_ * NH + h;
            if (proj < 2) {
                const size_t fb = (((size_t)bh * 128 + (s_ >> 4)) * 2 + (dk >> 5)) * 512
                                + (size_t)((((dk & 31) >> 3) * 16) + (s_ & 15)) * 8 + (dk & 7);
#pragma unroll
                for (int r = 0; r < 4; r++)
                    OutQK[fb + (size_t)r * 8] = f2bf(fmaxf(acc[i][j][r] + bb, 0.f));
            } else {
                const size_t fb = ((((size_t)bh * 32 + (s_ >> 6)) * 4 + (dk >> 4)) * 2
                                   + ((s_ >> 5) & 1)) * 512
                                + (size_t)((((s_ & 31) >> 3) * 16) + (dk & 15)) * 8 + (s_ & 7);
                uint2 pk;
                pk.x = (unsigned)f2bf(fmaxf(acc[i][j][0] + bb, 0.f))
                     | ((unsigned)f2bf(fmaxf(acc[i][j][1] + bb, 0.f)) << 16);
                pk.y = (unsigned)f2bf(fmaxf(acc[i][j][2] + bb, 0.f))
                     | ((unsigned)f2bf(fmaxf(acc[i][j][3] + bb, 0.f)) << 16);
                *(uint2*)&Vo[fb] = pk;
            }
        }
    }
}

// ---------------------------------------------------------------------------
// flash attention, bf16 MFMA. R17: occupancy 2 -> 4 blocks/CU.
// Post-mortem R16: VALU 50%, MFMA 31%, conflicts 0. Arithmetic: total attn
// VALU work ~30k cyc/SIMD -> ~13us at full issue; we run 47.8us at 50% VALU
// because grid 512 = only 2 resident blocks/CU (4 waves/SIMD, barrier-locked
// in pairs). The old "barrier drain" theory is dead: prefetch has the whole
// ~3600-cyc compute phase to land, so the vmcnt(0) drain is nearly free.
// Fix: 64-query blocks (grid 1024 = 4/CU = 8 waves/SIMD = 2048 thr/CU max),
// 64-key tiles (KVs 2x8KB, total LDS ~35KB allows 4 blocks/CU), per-wave
// state trimmed (acc[4]+accl+qa+qb ~ 28 regs -> VGPR ~50 <= 64 so 8 waves/
// SIMD is legal). Same math: permlane P-transpose, ones-MFMA l-sum. Barriers
// double per block but 4 independent blocks interleave phases (m114).
// ---------------------------------------------------------------------------
__global__ __launch_bounds__(512, 8) void attn_kernel(
    const unsigned short* __restrict__ Qf,
    const unsigned short* __restrict__ Kf,
    const unsigned short* __restrict__ Vf,
    unsigned short* __restrict__ ctxb)
{
    __shared__ __align__(16) unsigned short KVs[2][8192];  // [buf][K 8KB | V 8KB]
    __shared__ float Lx[4][64];                            // [qq][lane]

    const int blk = blockIdx.x;                // 0..1023
    const int xcd = blk & 7;
    const int j_  = blk >> 3;                  // 0..127
    const int bh  = xcd * 4 + (j_ & 3);        // 4 heads per XCD (K/V 2MB/XCD, L2-fit)
    const int qt  = j_ >> 2;                   // 0..31: 64-query tile

    const int tid  = threadIdx.x;
    const int wv   = tid >> 6;                 // 0..7
    const int lane = tid & 63;
    const int lq   = lane & 15;
    const int g    = lane >> 4;
    const int qq   = wv >> 1;                  // query sixteenth: 16 queries
    const int kh   = wv & 1;                   // key half of the 64-key tile

    const int q0 = qt * 64 + qq * 16;

    // ---- Q fragments: one 16-query chunk ----
    const size_t qfB = ((size_t)bh * 128 + (q0 >> 4)) * 1024 + (size_t)lane * 8;
    bf16x8 qa = *(const bf16x8*)&Qf[qfB];
    bf16x8 qb = *(const bf16x8*)&Qf[qfB + 512];

    const float C  = 0.18033688011112042f;   // log2(e)/8
    const float MC = 2.8853900817779267f;    // 16*C fixed shift (scores >= 0)

    // all-ones bf16 A-fragment for the l-sum MFMA (1.0 = 0x3F80)
    const short one_bf = (short)0x3F80;
    const bf16x8 ones8 = (bf16x8){one_bf, one_bf, one_bf, one_bf,
                                  one_bf, one_bf, one_bf, one_bf};

    const unsigned short* KtB = &Kf[(size_t)bh * 131072];
    const unsigned short* VtB = &Vf[(size_t)bh * 131072];

    floatx4 accl = (floatx4){0.f, 0.f, 0.f, 0.f};
    floatx4 acc[4];
#pragma unroll
    for (int n = 0; n < 4; n++) acc[n] = (floatx4){0.f, 0.f, 0.f, 0.f};

    // ---- stage tile 0 into buf 0: wave wv copies K chunk wv, V chunk wv ----
    gld16(&KtB[(size_t)wv * 512 + lane * 8], &KVs[0][wv * 512]);
    gld16(&VtB[(size_t)wv * 512 + lane * 8], &KVs[0][4096 + wv * 512]);
    __syncthreads();   // compiler drains vmcnt before s_barrier

    for (int jt = 0; jt < SEQ / 64; jt++) {
        const int buf = jt & 1;

        // ---- prefetch next 64-key tile into the other buffer ----
        const int jn = (jt + 1) & (SEQ / 64 - 1);
        gld16(&KtB[(size_t)jn * 4096 + wv * 512 + lane * 8], &KVs[buf ^ 1][wv * 512]);
        gld16(&VtB[(size_t)jn * 4096 + wv * 512 + lane * 8], &KVs[buf ^ 1][4096 + wv * 512]);

        const unsigned short* kb = &KVs[buf][0];
        const unsigned short* vb = &KVs[buf][4096];

        // ---- this wave's 32-key half ----
        bf16x8 a0 = *(const bf16x8*)&kb[(2 * kh + 0) * 1024 + lane * 8];
        bf16x8 a1 = *(const bf16x8*)&kb[(2 * kh + 0) * 1024 + 512 + lane * 8];
        bf16x8 a2 = *(const bf16x8*)&kb[(2 * kh + 1) * 1024 + lane * 8];
        bf16x8 a3 = *(const bf16x8*)&kb[(2 * kh + 1) * 1024 + 512 + lane * 8];
        bf16x8 vr[4];
#pragma unroll
        for (int n = 0; n < 4; n++)
            vr[n] = *(const bf16x8*)&vb[(n * 2 + kh) * 512 + lane * 8];

        floatx4 s0 = (floatx4){0.f, 0.f, 0.f, 0.f};
        floatx4 s1 = (floatx4){0.f, 0.f, 0.f, 0.f};
        s0 = __builtin_amdgcn_mfma_f32_16x16x32_bf16(a0, qa, s0, 0, 0, 0);
        s0 = __builtin_amdgcn_mfma_f32_16x16x32_bf16(a1, qb, s0, 0, 0, 0);
        s1 = __builtin_amdgcn_mfma_f32_16x16x32_bf16(a2, qa, s1, 0, 0, 0);
        s1 = __builtin_amdgcn_mfma_f32_16x16x32_bf16(a3, qb, s1, 0, 0, 0);

        float p00 = __builtin_amdgcn_exp2f(fmaf(s0[0], C, -MC));
        float p01 = __builtin_amdgcn_exp2f(fmaf(s0[1], C, -MC));
        float p02 = __builtin_amdgcn_exp2f(fmaf(s0[2], C, -MC));
        float p03 = __builtin_amdgcn_exp2f(fmaf(s0[3], C, -MC));
        unsigned d0 = pk2bf(p00, p01);
        unsigned d1 = pk2bf(p02, p03);

        float p10 = __builtin_amdgcn_exp2f(fmaf(s1[0], C, -MC));
        float p11 = __builtin_amdgcn_exp2f(fmaf(s1[1], C, -MC));
        float p12 = __builtin_amdgcn_exp2f(fmaf(s1[2], C, -MC));
        float p13 = __builtin_amdgcn_exp2f(fmaf(s1[3], C, -MC));
        unsigned d2 = pk2bf(p10, p11);
        unsigned d3 = pk2bf(p12, p13);

        // in-register transpose: lane=(p1,g1'), reg=(g0',p0)
        uintx2 r02 = __builtin_amdgcn_permlane32_swap(d0, d2, false, false);
        uintx2 r13 = __builtin_amdgcn_permlane32_swap(d1, d3, false, false);
        uintx2 f02 = __builtin_amdgcn_permlane16_swap(r02.x, r02.y, false, false);
        uintx2 f13 = __builtin_amdgcn_permlane16_swap(r13.x, r13.y, false, false);

        union { unsigned u[4]; bf16x8 v; } pbu;
        pbu.u[0] = f02.x;   // keys 8g+0,1
        pbu.u[1] = f13.x;   // keys 8g+2,3
        pbu.u[2] = f02.y;   // keys 8g+4,5
        pbu.u[3] = f13.y;   // keys 8g+6,7

        // softmax denominator on the MFMA pipe: D[*,q] = sum_k P[k,q]
        accl = __builtin_amdgcn_mfma_f32_16x16x32_bf16(ones8, pbu.v, accl, 0, 0, 0);

#pragma unroll
        for (int n = 0; n < 4; n++)
            acc[n] = __builtin_amdgcn_mfma_f32_16x16x32_bf16(vr[n], pbu.v, acc[n], 0, 0, 0);

        __syncthreads();   // staging of buf^1 complete + all waves done with buf
    }

    // ---- cross-wave partner reduction: kh=1 -> LDS (dead KV buffers) -> kh=0 ----
    float* red = (float*)&KVs[0][0] + (size_t)qq * 1024;   // 4KB region per qq
    if (kh == 1) {
        Lx[qq][lane] = accl[0];
#pragma unroll
        for (int n = 0; n < 4; n++)
            *(floatx4*)&red[n * 256 + lane * 4] = acc[n];
    }
    __syncthreads();
    if (kh == 0) {
        const int b_ = bh >> 4, h_ = bh & 15;
        const float lt = accl[0] + Lx[qq][lane];
        const float li = 1.f / lt;
#pragma unroll
        for (int n = 0; n < 4; n++) {
            floatx4 a = acc[n];
            floatx4 b = *(const floatx4*)&red[n * 256 + lane * 4];
            uint2 pk;
            pk.x = pk2bf((a[0] + b[0]) * li, (a[1] + b[1]) * li);
            pk.y = pk2bf((a[2] + b[2]) * li, (a[3] + b[3]) * li);
            *(uint2*)&ctxb[((size_t)(b_ * SEQ) + q0 + lq) * D_MODEL
                           + h_ * DK + n * 16 + g * 4] = pk;
        }
    }
}

// ---------------------------------------------------------------------------
// gemm_o (R13 64x64 retile, kept)
// ---------------------------------------------------------------------------
__global__ __launch_bounds__(256) void gemm_o(
    const unsigned short* __restrict__ Abf,
    const unsigned short* __restrict__ Bp,
    const float* __restrict__ bo,
    float* __restrict__ out)
{
    __shared__ __align__(16) unsigned short As[64 * 32];
    __shared__ __align__(16) unsigned short Bs[64 * 32];

    const int tid  = threadIdx.x;
    const int wv   = tid >> 6, lane = tid & 63;
    const int bid  = blockIdx.x;
    const int swz  = (bid & 7) * 128 + (bid >> 3);
    const int m0   = (swz & 63) * 64;
    const int n0   = (swz >> 6) * 64;
    const int lq   = lane & 15, g = lane >> 4;
    const int wm   = (wv >> 1) * 32;
    const int wn   = (wv & 1) * 32;
    const int srow = lane >> 2;
    const int sseg = (lane & 3) * 8;

    floatx4 acc[2][2];
#pragma unroll
    for (int i = 0; i < 2; i++)
#pragma unroll
        for (int j = 0; j < 2; j++) acc[i][j] = (floatx4){0.f, 0.f, 0.f, 0.f};

    for (int k0 = 0; k0 < 1024; k0 += 32) {
        const int row = wv * 16 + srow;
        gld16(&Abf[(size_t)(m0 + row) * 1024 + k0 + sseg], &As[wv * 512]);
        gld16(&Bp [(size_t)(n0 + row) * 1024 + k0 + sseg], &Bs[wv * 512]);
        __syncthreads();
        bf16x8 af[2], bfv[2];
#pragma unroll
        for (int i = 0; i < 2; i++)
            af[i] = *(const bf16x8*)&As[(wm + i * 16 + lq) * 32 + g * 8];
#pragma unroll
        for (int j = 0; j < 2; j++)
            bfv[j] = *(const bf16x8*)&Bs[(wn + j * 16 + lq) * 32 + g * 8];
#pragma unroll
        for (int i = 0; i < 2; i++)
#pragma unroll
            for (int j = 0; j < 2; j++)
                acc[i][j] = __builtin_amdgcn_mfma_f32_16x16x32_bf16(af[i], bfv[j], acc[i][j], 0, 0, 0);
        __syncthreads();
    }

#pragma unroll
    for (int j = 0; j < 2; j++) {
        const int n  = n0 + wn + j * 16 + lq;
        const float bb = bo[n];
#pragma unroll
        for (int i = 0; i < 2; i++) {
#pragma unroll
            for (int r = 0; r < 4; r++) {
                const int m = m0 + wm + i * 16 + g * 4 + r;
                out[(size_t)m * 1024 + n] = fmaxf(acc[i][j][r] + bb, 0.f);
            }
        }
    }
}

extern "C" void kernel_launch(void* const* d_in, const int* in_sizes, int n_in,
                              void* d_out, int out_size, void* d_ws, size_t ws_size,
                              hipStream_t stream) {
    const float* x  = (const float*)d_in[0];
    const float* Wq = (const float*)d_in[1];
    const float* bq = (const float*)d_in[2];
    const float* Wk = (const float*)d_in[3];
    const float* bk = (const float*)d_in[4];
    const float* Wv = (const float*)d_in[5];
    const float* bv = (const float*)d_in[6];
    const float* Wo = (const float*)d_in[7];
    const float* bo = (const float*)d_in[8];
    float* out = (float*)d_out;

    const size_t perE = (size_t)NB * NH * SEQ * DK;      // 4,194,304
    unsigned short* xbf  = (unsigned short*)d_ws;        // 8 MB
    unsigned short* Bqkv = xbf  + (size_t)4096 * 1024;   // 6 MB
    unsigned short* Bo   = Bqkv + (size_t)3072 * 1024;   // 2 MB
    unsigned short* Qfr  = Bo   + (size_t)1024 * 1024;   // 8 MB (fragment layout)
    unsigned short* Kfr  = Qfr + perE;                   // 8 MB
    unsigned short* Vfr  = Kfr + perE;                   // 8 MB
    unsigned short* Cbf  = Vfr + perE;                   // 8 MB

    prep<<<2048, 256, 0, stream>>>(x, xbf, Wq, Wk, Wv, Wo, Bqkv, Bo);
    gemm_qkv<<<dim3(32, 24), 256, 0, stream>>>(xbf, Bqkv, bq, bk, bv, Qfr, Kfr, Vfr);
    attn_kernel<<<1024, 512, 0, stream>>>(Qfr, Kfr, Vfr, Cbf);
    gemm_o<<<1024, 256, 0, stream>>>(Cbf, Bo, bo, out);
}

// Round 9
// 188.801 us; speedup vs baseline: 1.0083x; 1.0083x over previous
//
#include <hip/hip_runtime.h>
#include <cstddef>

#define D_MODEL 1024
#define DK 64
#define NH 16
#define NB 2
#define SEQ 2048

typedef __attribute__((ext_vector_type(8))) short bf16x8;
typedef __attribute__((ext_vector_type(4))) float floatx4;
typedef __attribute__((ext_vector_type(2))) unsigned uintx2;

static __device__ __forceinline__ unsigned short f2bf(float f) {
    union { float f; unsigned u; } v; v.f = f;
    unsigned r = (v.u + 0x7fffu + ((v.u >> 16) & 1u)) >> 16;
    return (unsigned short)r;
}

// pack two floats' bf16 (round-half-away) into one dword
static __device__ __forceinline__ unsigned pk2bf(float lo, float hi) {
    unsigned ua = __float_as_uint(lo) + 0x8000u;
    unsigned ub = __float_as_uint(hi) + 0x8000u;
    return __builtin_amdgcn_perm(ub, ua, 0x07060302u);
}

static __device__ __forceinline__ void gld16(const unsigned short* g, unsigned short* l) {
    __builtin_amdgcn_global_load_lds(
        (const __attribute__((address_space(1))) unsigned int*)g,
        (__attribute__((address_space(3))) unsigned int*)l, 16, 0, 0);
}

// ---------------------------------------------------------------------------
// prep: fused convert_x (blocks 0..1023) + pack_w (blocks 1024..2047).
// ---------------------------------------------------------------------------
__global__ __launch_bounds__(256) void prep(
    const float* __restrict__ x, unsigned short* __restrict__ xb,
    const float* __restrict__ Wq, const float* __restrict__ Wk,
    const float* __restrict__ Wv, const float* __restrict__ Wo,
    unsigned short* __restrict__ Bqkv, unsigned short* __restrict__ Bo)
{
    __shared__ float T[64][65];
    const int tid = threadIdx.x;

    if (blockIdx.x < 1024) {
        const size_t i = ((size_t)blockIdx.x * 256 + tid) * 16;
#pragma unroll
        for (int c = 0; c < 16; c += 4) {
            float4 v = *(const float4*)&x[i + c];
            uint2 pk;
            pk.x = (unsigned)f2bf(v.x) | ((unsigned)f2bf(v.y) << 16);
            pk.y = (unsigned)f2bf(v.z) | ((unsigned)f2bf(v.w) << 16);
            *(uint2*)&xb[i + c] = pk;
        }
        return;
    }

    const int t   = blockIdx.x - 1024;
    const int rr   = tid >> 2;
    const int cseg = (tid & 3) * 16;

    const float* src;
    unsigned short* dst;
    if (t < 768) {
        const int proj = t / 256, rem = t % 256;
        const int h = rem >> 4, d0 = (rem & 15) * 64;
        const float* W = proj == 0 ? Wq : (proj == 1 ? Wk : Wv);
        src = W + ((size_t)h * 1024 + d0) * 64;
#pragma unroll
        for (int c = 0; c < 16; c += 4) {
            float4 v = *(const float4*)&src[(size_t)rr * 64 + cseg + c];
            T[rr][cseg + c + 0] = v.x; T[rr][cseg + c + 1] = v.y;
            T[rr][cseg + c + 2] = v.z; T[rr][cseg + c + 3] = v.w;
        }
        __syncthreads();
        dst = &Bqkv[((size_t)proj * 1024 + h * 64 + rr) * 1024 + d0 + cseg];
    } else {
        const int t2 = t - 768;
        const int k0 = (t2 >> 4) * 64, nb0 = (t2 & 15) * 64;
#pragma unroll
        for (int c = 0; c < 16; c += 4) {
            float4 v = *(const float4*)&Wo[(size_t)(k0 + rr) * 1024 + nb0 + cseg + c];
            T[rr][cseg + c + 0] = v.x; T[rr][cseg + c + 1] = v.y;
            T[rr][cseg + c + 2] = v.z; T[rr][cseg + c + 3] = v.w;
        }
        __syncthreads();
        dst = &Bo[(size_t)(nb0 + rr) * 1024 + k0 + cseg];
    }
    unsigned int w[8];
#pragma unroll
    for (int ii = 0; ii < 8; ii++) {
        unsigned short lo = f2bf(T[cseg + ii * 2 + 0][rr]);
        unsigned short hi = f2bf(T[cseg + ii * 2 + 1][rr]);
        w[ii] = (unsigned)lo | ((unsigned)hi << 16);
    }
    *(uint4*)(dst + 0) = make_uint4(w[0], w[1], w[2], w[3]);
    *(uint4*)(dst + 8) = make_uint4(w[4], w[5], w[6], w[7]);
}

// ---------------------------------------------------------------------------
// gemm_qkv (R14/BK=32, unchanged)
// ---------------------------------------------------------------------------
__global__ __launch_bounds__(256) void gemm_qkv(
    const unsigned short* __restrict__ Abf,
    const unsigned short* __restrict__ Bp,
    const float* __restrict__ bq, const float* __restrict__ bk,
    const float* __restrict__ bv,
    unsigned short* __restrict__ Qo, unsigned short* __restrict__ Ko,
    unsigned short* __restrict__ Vo)
{
    __shared__ __align__(16) unsigned short As[128 * 32];
    __shared__ __align__(16) unsigned short Bs[128 * 32];

    const int tid  = threadIdx.x;
    const int wv   = tid >> 6, lane = tid & 63;
    const int m0   = blockIdx.x * 128;
    const int n0   = blockIdx.y * 128;
    const int lq   = lane & 15, g = lane >> 4;
    const int wm   = (wv >> 1) * 64;
    const int wn   = (wv & 1) * 64;
    const int srow = lane >> 2;
    const int sseg = (lane & 3) * 8;

    floatx4 acc[4][4];
#pragma unroll
    for (int i = 0; i < 4; i++)
#pragma unroll
        for (int j = 0; j < 4; j++) acc[i][j] = (floatx4){0.f, 0.f, 0.f, 0.f};

    for (int k0 = 0; k0 < 1024; k0 += 32) {
#pragma unroll
        for (int r = 0; r < 2; r++) {
            const int chunk = wv * 2 + r;
            const int row   = chunk * 16 + srow;
            gld16(&Abf[(size_t)(m0 + row) * 1024 + k0 + sseg], &As[chunk * 512]);
            gld16(&Bp [(size_t)(n0 + row) * 1024 + k0 + sseg], &Bs[chunk * 512]);
        }
        __syncthreads();
        bf16x8 af[4], bfv[4];
#pragma unroll
        for (int i = 0; i < 4; i++)
            af[i] = *(const bf16x8*)&As[(wm + i * 16 + lq) * 32 + g * 8];
#pragma unroll
        for (int j = 0; j < 4; j++)
            bfv[j] = *(const bf16x8*)&Bs[(wn + j * 16 + lq) * 32 + g * 8];
#pragma unroll
        for (int i = 0; i < 4; i++)
#pragma unroll
            for (int j = 0; j < 4; j++)
                acc[i][j] = __builtin_amdgcn_mfma_f32_16x16x32_bf16(af[i], bfv[j], acc[i][j], 0, 0, 0);
        __syncthreads();
    }

    const int proj = n0 >> 10;
    const float* bias = proj == 0 ? bq : (proj == 1 ? bk : bv);
    unsigned short* OutQK = proj == 0 ? Qo : Ko;

#pragma unroll
    for (int j = 0; j < 4; j++) {
        const int n  = n0 + wn + j * 16 + lq;
        const int nn = n & 1023;
        const int h  = nn >> 6, dk = nn & 63;
        const float bb = bias[nn];
#pragma unroll
        for (int i = 0; i < 4; i++) {
            const int mbase = m0 + wm + i * 16 + g * 4;
            const int b_ = mbase >> 11;
            const int s_ = mbase & (SEQ - 1);
            const int bh = b_ * NH + h;
            if (proj < 2) {
                const size_t fb = (((size_t)bh * 128 + (s_ >> 4)) * 2 + (dk >> 5)) * 512
                                + (size_t)((((dk & 31) >> 3) * 16) + (s_ & 15)) * 8 + (dk & 7);
#pragma unroll
                for (int r = 0; r < 4; r++)
                    OutQK[fb + (size_t)r * 8] = f2bf(fmaxf(acc[i][j][r] + bb, 0.f));
            } else {
                const size_t fb = ((((size_t)bh * 32 + (s_ >> 6)) * 4 + (dk >> 4)) * 2
                                   + ((s_ >> 5) & 1)) * 512
                                + (size_t)((((s_ & 31) >> 3) * 16) + (dk & 15)) * 8 + (s_ & 7);
                uint2 pk;
                pk.x = (unsigned)f2bf(fmaxf(acc[i][j][0] + bb, 0.f))
                     | ((unsigned)f2bf(fmaxf(acc[i][j][1] + bb, 0.f)) << 16);
                pk.y = (unsigned)f2bf(fmaxf(acc[i][j][2] + bb, 0.f))
                     | ((unsigned)f2bf(fmaxf(acc[i][j][3] + bb, 0.f)) << 16);
                *(uint2*)&Vo[fb] = pk;
            }
        }
    }
}

// ---------------------------------------------------------------------------
// flash attention, bf16 MFMA. R18: convoy-breaking block topology.
// Post-mortem R17: occupancy 30->58% with dur WORSE (16q/wave halved K/V-read
// amortization; l-MFMA doubled). Real MFMA load is ~5% (MfmaUtil's 30% uses
// the gfx94x 32-cyc formula); attn = VALU 50% + ~45% bubbles, and occupancy
// never converts because every prior variant placed >=2 waves/SIMD per block,
// barrier-locked; co-resident blocks convoy into the same barrier phase ->
// periodic whole-SIMD stalls.
// Fix: R16's exact per-wave work unit (32q x 32k, same ds_read amortization,
// permlane transpose, ones-MFMA l-sum) in 256-thread blocks (4 waves =
// qq{0,1} x kh{0,1}, 64-query tile, 64-key dbuf tiles). Grid 1024 = 4
// blocks/CU; each block = exactly 1 wave/SIMD -> each SIMD hosts 4 waves
// from 4 INDEPENDENT blocks; when one block barriers, three keep issuing.
// ---------------------------------------------------------------------------
__global__ __launch_bounds__(256, 4) void attn_kernel(
    const unsigned short* __restrict__ Qf,
    const unsigned short* __restrict__ Kf,
    const unsigned short* __restrict__ Vf,
    unsigned short* __restrict__ ctxb)
{
    __shared__ __align__(16) unsigned short KVs[2][8192];  // [buf][K 8KB | V 8KB]
    __shared__ float Lx[2][2][64];                         // [qq][t][lane]

    const int blk = blockIdx.x;                // 0..1023
    const int xcd = blk & 7;
    const int j_  = blk >> 3;                  // 0..127
    const int bh  = xcd * 4 + (j_ & 3);        // 4 heads per XCD (K/V+Q ~L2-fit)
    const int qt  = j_ >> 2;                   // 0..31: 64-query tile

    const int tid  = threadIdx.x;
    const int wv   = tid >> 6;                 // 0..3
    const int lane = tid & 63;
    const int lq   = lane & 15;
    const int g    = lane >> 4;
    const int qq   = wv >> 1;                  // query half of tile: 32 queries
    const int kh   = wv & 1;                   // key half of the 64-key tile

    const int q0 = qt * 64 + qq * 32;

    // ---- Q fragments: 2 query-tiles x 2 k-chunks (32 queries) ----
    bf16x8 qa[2], qb[2];
    const size_t qfB = ((size_t)bh * 128 + (q0 >> 4)) * 1024 + (size_t)lane * 8;
#pragma unroll
    for (int t = 0; t < 2; t++) {
        qa[t] = *(const bf16x8*)&Qf[qfB + (size_t)t * 1024];
        qb[t] = *(const bf16x8*)&Qf[qfB + (size_t)t * 1024 + 512];
    }

    const float C  = 0.18033688011112042f;   // log2(e)/8
    const float MC = 2.8853900817779267f;    // 16*C fixed shift (scores >= 0)

    // all-ones bf16 A-fragment for the l-sum MFMA (1.0 = 0x3F80)
    const short one_bf = (short)0x3F80;
    const bf16x8 ones8 = (bf16x8){one_bf, one_bf, one_bf, one_bf,
                                  one_bf, one_bf, one_bf, one_bf};

    const unsigned short* KtB = &Kf[(size_t)bh * 131072];
    const unsigned short* VtB = &Vf[(size_t)bh * 131072];

    floatx4 accl[2];
    floatx4 acc[2][4];                         // [qtile][dk-tile]
#pragma unroll
    for (int t = 0; t < 2; t++) {
        accl[t] = (floatx4){0.f, 0.f, 0.f, 0.f};
#pragma unroll
        for (int n = 0; n < 4; n++) acc[t][n] = (floatx4){0.f, 0.f, 0.f, 0.f};
    }

    // ---- stage tile 0 into buf 0: wave wv copies K,V chunks 2wv,2wv+1 ----
#pragma unroll
    for (int r = 0; r < 2; r++) {
        const int c = wv * 2 + r;
        gld16(&KtB[(size_t)c * 512 + lane * 8], &KVs[0][c * 512]);
        gld16(&VtB[(size_t)c * 512 + lane * 8], &KVs[0][4096 + c * 512]);
    }
    __syncthreads();   // compiler drains vmcnt before s_barrier

    for (int jt = 0; jt < SEQ / 64; jt++) {
        const int buf = jt & 1;

        // ---- prefetch next 64-key tile into the other buffer ----
        const int jn = (jt + 1) & (SEQ / 64 - 1);
        const unsigned short* ktn = &KtB[(size_t)jn * 4096];
        const unsigned short* vtn = &VtB[(size_t)jn * 4096];
#pragma unroll
        for (int r = 0; r < 2; r++) {
            const int c = wv * 2 + r;
            gld16(&ktn[(size_t)c * 512 + lane * 8], &KVs[buf ^ 1][c * 512]);
            gld16(&vtn[(size_t)c * 512 + lane * 8], &KVs[buf ^ 1][4096 + c * 512]);
        }

        const unsigned short* kb = &KVs[buf][0];
        const unsigned short* vb = &KVs[buf][4096];

        // ---- this wave's 32-key half (a0..a3) + V fragments ----
        bf16x8 a0 = *(const bf16x8*)&kb[(2 * kh + 0) * 1024 + lane * 8];
        bf16x8 a1 = *(const bf16x8*)&kb[(2 * kh + 0) * 1024 + 512 + lane * 8];
        bf16x8 a2 = *(const bf16x8*)&kb[(2 * kh + 1) * 1024 + lane * 8];
        bf16x8 a3 = *(const bf16x8*)&kb[(2 * kh + 1) * 1024 + 512 + lane * 8];
        bf16x8 vr[4];
#pragma unroll
        for (int n = 0; n < 4; n++)
            vr[n] = *(const bf16x8*)&vb[(n * 2 + kh) * 512 + lane * 8];

#pragma unroll
        for (int t = 0; t < 2; t++) {
            floatx4 s0 = (floatx4){0.f, 0.f, 0.f, 0.f};
            floatx4 s1 = (floatx4){0.f, 0.f, 0.f, 0.f};
            s0 = __builtin_amdgcn_mfma_f32_16x16x32_bf16(a0, qa[t], s0, 0, 0, 0);
            s0 = __builtin_amdgcn_mfma_f32_16x16x32_bf16(a1, qb[t], s0, 0, 0, 0);
            s1 = __builtin_amdgcn_mfma_f32_16x16x32_bf16(a2, qa[t], s1, 0, 0, 0);
            s1 = __builtin_amdgcn_mfma_f32_16x16x32_bf16(a3, qb[t], s1, 0, 0, 0);

            float p00 = __builtin_amdgcn_exp2f(fmaf(s0[0], C, -MC));
            float p01 = __builtin_amdgcn_exp2f(fmaf(s0[1], C, -MC));
            float p02 = __builtin_amdgcn_exp2f(fmaf(s0[2], C, -MC));
            float p03 = __builtin_amdgcn_exp2f(fmaf(s0[3], C, -MC));
            unsigned d0 = pk2bf(p00, p01);
            unsigned d1 = pk2bf(p02, p03);

            float p10 = __builtin_amdgcn_exp2f(fmaf(s1[0], C, -MC));
            float p11 = __builtin_amdgcn_exp2f(fmaf(s1[1], C, -MC));
            float p12 = __builtin_amdgcn_exp2f(fmaf(s1[2], C, -MC));
            float p13 = __builtin_amdgcn_exp2f(fmaf(s1[3], C, -MC));
            unsigned d2 = pk2bf(p10, p11);
            unsigned d3 = pk2bf(p12, p13);

            // in-register transpose: lane=(p1,g1'), reg=(g0',p0)
            uintx2 r02 = __builtin_amdgcn_permlane32_swap(d0, d2, false, false);
            uintx2 r13 = __builtin_amdgcn_permlane32_swap(d1, d3, false, false);
            uintx2 f02 = __builtin_amdgcn_permlane16_swap(r02.x, r02.y, false, false);
            uintx2 f13 = __builtin_amdgcn_permlane16_swap(r13.x, r13.y, false, false);

            union { unsigned u[4]; bf16x8 v; } pbu;
            pbu.u[0] = f02.x;   // keys 8g+0,1
            pbu.u[1] = f13.x;   // keys 8g+2,3
            pbu.u[2] = f02.y;   // keys 8g+4,5
            pbu.u[3] = f13.y;   // keys 8g+6,7

            // softmax denominator on the MFMA pipe: D[*,q] = sum_k P[k,q]
            accl[t] = __builtin_amdgcn_mfma_f32_16x16x32_bf16(ones8, pbu.v, accl[t], 0, 0, 0);

#pragma unroll
            for (int n = 0; n < 4; n++)
                acc[t][n] = __builtin_amdgcn_mfma_f32_16x16x32_bf16(vr[n], pbu.v, acc[t][n], 0, 0, 0);
        }

        __syncthreads();   // staging of buf^1 complete + all waves done with buf
    }

    // ---- cross-wave partner reduction: kh=1 -> LDS (dead KV buffer) -> kh=0 ----
    float* red = (float*)&KVs[0][0] + (size_t)qq * 2048;   // 8KB region per qq
    if (kh == 1) {
#pragma unroll
        for (int t = 0; t < 2; t++) {
            Lx[qq][t][lane] = accl[t][0];
#pragma unroll
            for (int n = 0; n < 4; n++)
                *(floatx4*)&red[(t * 4 + n) * 256 + lane * 4] = acc[t][n];
        }
    }
    __syncthreads();
    if (kh == 0) {
        const int b_ = bh >> 4, h_ = bh & 15;
#pragma unroll
        for (int t = 0; t < 2; t++) {
            const float lt = accl[t][0] + Lx[qq][t][lane];
            const float li = 1.f / lt;
#pragma unroll
            for (int n = 0; n < 4; n++) {
                floatx4 a = acc[t][n];
                floatx4 b = *(const floatx4*)&red[(t * 4 + n) * 256 + lane * 4];
                uint2 pk;
                pk.x = pk2bf((a[0] + b[0]) * li, (a[1] + b[1]) * li);
                pk.y = pk2bf((a[2] + b[2]) * li, (a[3] + b[3]) * li);
                *(uint2*)&ctxb[((size_t)(b_ * SEQ) + q0 + t * 16 + lq) * D_MODEL
                               + h_ * DK + n * 16 + g * 4] = pk;
            }
        }
    }
}

// ---------------------------------------------------------------------------
// gemm_o (R13 64x64 retile, kept)
// ---------------------------------------------------------------------------
__global__ __launch_bounds__(256) void gemm_o(
    const unsigned short* __restrict__ Abf,
    const unsigned short* __restrict__ Bp,
    const float* __restrict__ bo,
    float* __restrict__ out)
{
    __shared__ __align__(16) unsigned short As[64 * 32];
    __shared__ __align__(16) unsigned short Bs[64 * 32];

    const int tid  = threadIdx.x;
    const int wv   = tid >> 6, lane = tid & 63;
    const int bid  = blockIdx.x;
    const int swz  = (bid & 7) * 128 + (bid >> 3);
    const int m0   = (swz & 63) * 64;
    const int n0   = (swz >> 6) * 64;
    const int lq   = lane & 15, g = lane >> 4;
    const int wm   = (wv >> 1) * 32;
    const int wn   = (wv & 1) * 32;
    const int srow = lane >> 2;
    const int sseg = (lane & 3) * 8;

    floatx4 acc[2][2];
#pragma unroll
    for (int i = 0; i < 2; i++)
#pragma unroll
        for (int j = 0; j < 2; j++) acc[i][j] = (floatx4){0.f, 0.f, 0.f, 0.f};

    for (int k0 = 0; k0 < 1024; k0 += 32) {
        const int row = wv * 16 + srow;
        gld16(&Abf[(size_t)(m0 + row) * 1024 + k0 + sseg], &As[wv * 512]);
        gld16(&Bp [(size_t)(n0 + row) * 1024 + k0 + sseg], &Bs[wv * 512]);
        __syncthreads();
        bf16x8 af[2], bfv[2];
#pragma unroll
        for (int i = 0; i < 2; i++)
            af[i] = *(const bf16x8*)&As[(wm + i * 16 + lq) * 32 + g * 8];
#pragma unroll
        for (int j = 0; j < 2; j++)
            bfv[j] = *(const bf16x8*)&Bs[(wn + j * 16 + lq) * 32 + g * 8];
#pragma unroll
        for (int i = 0; i < 2; i++)
#pragma unroll
            for (int j = 0; j < 2; j++)
                acc[i][j] = __builtin_amdgcn_mfma_f32_16x16x32_bf16(af[i], bfv[j], acc[i][j], 0, 0, 0);
        __syncthreads();
    }

#pragma unroll
    for (int j = 0; j < 2; j++) {
        const int n  = n0 + wn + j * 16 + lq;
        const float bb = bo[n];
#pragma unroll
        for (int i = 0; i < 2; i++) {
#pragma unroll
            for (int r = 0; r < 4; r++) {
                const int m = m0 + wm + i * 16 + g * 4 + r;
                out[(size_t)m * 1024 + n] = fmaxf(acc[i][j][r] + bb, 0.f);
            }
        }
    }
}

extern "C" void kernel_launch(void* const* d_in, const int* in_sizes, int n_in,
                              void* d_out, int out_size, void* d_ws, size_t ws_size,
                              hipStream_t stream) {
    const float* x  = (const float*)d_in[0];
    const float* Wq = (const float*)d_in[1];
    const float* bq = (const float*)d_in[2];
    const float* Wk = (const float*)d_in[3];
    const float* bk = (const float*)d_in[4];
    const float* Wv = (const float*)d_in[5];
    const float* bv = (const float*)d_in[6];
    const float* Wo = (const float*)d_in[7];
    const float* bo = (const float*)d_in[8];
    float* out = (float*)d_out;

    const size_t perE = (size_t)NB * NH * SEQ * DK;      // 4,194,304
    unsigned short* xbf  = (unsigned short*)d_ws;        // 8 MB
    unsigned short* Bqkv = xbf  + (size_t)4096 * 1024;   // 6 MB
    unsigned short* Bo   = Bqkv + (size_t)3072 * 1024;   // 2 MB
    unsigned short* Qfr  = Bo   + (size_t)1024 * 1024;   // 8 MB (fragment layout)
    unsigned short* Kfr  = Qfr + perE;                   // 8 MB
    unsigned short* Vfr  = Kfr + perE;                   // 8 MB
    unsigned short* Cbf  = Vfr + perE;                   // 8 MB

    prep<<<2048, 256, 0, stream>>>(x, xbf, Wq, Wk, Wv, Wo, Bqkv, Bo);
    gemm_qkv<<<dim3(32, 24), 256, 0, stream>>>(xbf, Bqkv, bq, bk, bv, Qfr, Kfr, Vfr);
    attn_kernel<<<1024, 256, 0, stream>>>(Qfr, Kfr, Vfr, Cbf);
    gemm_o<<<1024, 256, 0, stream>>>(Cbf, Bo, bo, out);
}

// Round 10
// 181.659 us; speedup vs baseline: 1.0479x; 1.0393x over previous
//
#include <hip/hip_runtime.h>
#include <cstddef>

#define D_MODEL 1024
#define DK 64
#define NH 16
#define NB 2
#define SEQ 2048

typedef __attribute__((ext_vector_type(8))) short bf16x8;
typedef __attribute__((ext_vector_type(4))) float floatx4;
typedef __attribute__((ext_vector_type(2))) unsigned uintx2;

static __device__ __forceinline__ unsigned short f2bf(float f) {
    union { float f; unsigned u; } v; v.f = f;
    unsigned r = (v.u + 0x7fffu + ((v.u >> 16) & 1u)) >> 16;
    return (unsigned short)r;
}

// pack two floats' bf16 (round-half-away) into one dword
static __device__ __forceinline__ unsigned pk2bf(float lo, float hi) {
    unsigned ua = __float_as_uint(lo) + 0x8000u;
    unsigned ub = __float_as_uint(hi) + 0x8000u;
    return __builtin_amdgcn_perm(ub, ua, 0x07060302u);
}

// packed f32x2 -> bf16x2 in ONE VALU op (RNE rounding); replaces 3-op pk2bf
// in the attn hot loop (T12 primitive; pure-VALU asm, no scheduling hazard).
static __device__ __forceinline__ unsigned cvtpk(float lo, float hi) {
    unsigned r;
    asm("v_cvt_pk_bf16_f32 %0, %1, %2" : "=v"(r) : "v"(lo), "v"(hi));
    return r;
}

static __device__ __forceinline__ void gld16(const unsigned short* g, unsigned short* l) {
    __builtin_amdgcn_global_load_lds(
        (const __attribute__((address_space(1))) unsigned int*)g,
        (__attribute__((address_space(3))) unsigned int*)l, 16, 0, 0);
}

// ---------------------------------------------------------------------------
// prep: fused convert_x (blocks 0..1023) + pack_w (blocks 1024..2047).
// ---------------------------------------------------------------------------
__global__ __launch_bounds__(256) void prep(
    const float* __restrict__ x, unsigned short* __restrict__ xb,
    const float* __restrict__ Wq, const float* __restrict__ Wk,
    const float* __restrict__ Wv, const float* __restrict__ Wo,
    unsigned short* __restrict__ Bqkv, unsigned short* __restrict__ Bo)
{
    __shared__ float T[64][65];
    const int tid = threadIdx.x;

    if (blockIdx.x < 1024) {
        const size_t i = ((size_t)blockIdx.x * 256 + tid) * 16;
#pragma unroll
        for (int c = 0; c < 16; c += 4) {
            float4 v = *(const float4*)&x[i + c];
            uint2 pk;
            pk.x = (unsigned)f2bf(v.x) | ((unsigned)f2bf(v.y) << 16);
            pk.y = (unsigned)f2bf(v.z) | ((unsigned)f2bf(v.w) << 16);
            *(uint2*)&xb[i + c] = pk;
        }
        return;
    }

    const int t   = blockIdx.x - 1024;
    const int rr   = tid >> 2;
    const int cseg = (tid & 3) * 16;

    const float* src;
    unsigned short* dst;
    if (t < 768) {
        const int proj = t / 256, rem = t % 256;
        const int h = rem >> 4, d0 = (rem & 15) * 64;
        const float* W = proj == 0 ? Wq : (proj == 1 ? Wk : Wv);
        src = W + ((size_t)h * 1024 + d0) * 64;
#pragma unroll
        for (int c = 0; c < 16; c += 4) {
            float4 v = *(const float4*)&src[(size_t)rr * 64 + cseg + c];
            T[rr][cseg + c + 0] = v.x; T[rr][cseg + c + 1] = v.y;
            T[rr][cseg + c + 2] = v.z; T[rr][cseg + c + 3] = v.w;
        }
        __syncthreads();
        dst = &Bqkv[((size_t)proj * 1024 + h * 64 + rr) * 1024 + d0 + cseg];
    } else {
        const int t2 = t - 768;
        const int k0 = (t2 >> 4) * 64, nb0 = (t2 & 15) * 64;
#pragma unroll
        for (int c = 0; c < 16; c += 4) {
            float4 v = *(const float4*)&Wo[(size_t)(k0 + rr) * 1024 + nb0 + cseg + c];
            T[rr][cseg + c + 0] = v.x; T[rr][cseg + c + 1] = v.y;
            T[rr][cseg + c + 2] = v.z; T[rr][cseg + c + 3] = v.w;
        }
        __syncthreads();
        dst = &Bo[(size_t)(nb0 + rr) * 1024 + k0 + cseg];
    }
    unsigned int w[8];
#pragma unroll
    for (int ii = 0; ii < 8; ii++) {
        unsigned short lo = f2bf(T[cseg + ii * 2 + 0][rr]);
        unsigned short hi = f2bf(T[cseg + ii * 2 + 1][rr]);
        w[ii] = (unsigned)lo | ((unsigned)hi << 16);
    }
    *(uint4*)(dst + 0) = make_uint4(w[0], w[1], w[2], w[3]);
    *(uint4*)(dst + 8) = make_uint4(w[4], w[5], w[6], w[7]);
}

// ---------------------------------------------------------------------------
// gemm_qkv (R14/BK=32, unchanged)
// ---------------------------------------------------------------------------
__global__ __launch_bounds__(256) void gemm_qkv(
    const unsigned short* __restrict__ Abf,
    const unsigned short* __restrict__ Bp,
    const float* __restrict__ bq, const float* __restrict__ bk,
    const float* __restrict__ bv,
    unsigned short* __restrict__ Qo, unsigned short* __restrict__ Ko,
    unsigned short* __restrict__ Vo)
{
    __shared__ __align__(16) unsigned short As[128 * 32];
    __shared__ __align__(16) unsigned short Bs[128 * 32];

    const int tid  = threadIdx.x;
    const int wv   = tid >> 6, lane = tid & 63;
    const int m0   = blockIdx.x * 128;
    const int n0   = blockIdx.y * 128;
    const int lq   = lane & 15, g = lane >> 4;
    const int wm   = (wv >> 1) * 64;
    const int wn   = (wv & 1) * 64;
    const int srow = lane >> 2;
    const int sseg = (lane & 3) * 8;

    floatx4 acc[4][4];
#pragma unroll
    for (int i = 0; i < 4; i++)
#pragma unroll
        for (int j = 0; j < 4; j++) acc[i][j] = (floatx4){0.f, 0.f, 0.f, 0.f};

    for (int k0 = 0; k0 < 1024; k0 += 32) {
#pragma unroll
        for (int r = 0; r < 2; r++) {
            const int chunk = wv * 2 + r;
            const int row   = chunk * 16 + srow;
            gld16(&Abf[(size_t)(m0 + row) * 1024 + k0 + sseg], &As[chunk * 512]);
            gld16(&Bp [(size_t)(n0 + row) * 1024 + k0 + sseg], &Bs[chunk * 512]);
        }
        __syncthreads();
        bf16x8 af[4], bfv[4];
#pragma unroll
        for (int i = 0; i < 4; i++)
            af[i] = *(const bf16x8*)&As[(wm + i * 16 + lq) * 32 + g * 8];
#pragma unroll
        for (int j = 0; j < 4; j++)
            bfv[j] = *(const bf16x8*)&Bs[(wn + j * 16 + lq) * 32 + g * 8];
#pragma unroll
        for (int i = 0; i < 4; i++)
#pragma unroll
            for (int j = 0; j < 4; j++)
                acc[i][j] = __builtin_amdgcn_mfma_f32_16x16x32_bf16(af[i], bfv[j], acc[i][j], 0, 0, 0);
        __syncthreads();
    }

    const int proj = n0 >> 10;
    const float* bias = proj == 0 ? bq : (proj == 1 ? bk : bv);
    unsigned short* OutQK = proj == 0 ? Qo : Ko;

#pragma unroll
    for (int j = 0; j < 4; j++) {
        const int n  = n0 + wn + j * 16 + lq;
        const int nn = n & 1023;
        const int h  = nn >> 6, dk = nn & 63;
        const float bb = bias[nn];
#pragma unroll
        for (int i = 0; i < 4; i++) {
            const int mbase = m0 + wm + i * 16 + g * 4;
            const int b_ = mbase >> 11;
            const int s_ = mbase & (SEQ - 1);
            const int bh = b_ * NH + h;
            if (proj < 2) {
                const size_t fb = (((size_t)bh * 128 + (s_ >> 4)) * 2 + (dk >> 5)) * 512
                                + (size_t)((((dk & 31) >> 3) * 16) + (s_ & 15)) * 8 + (dk & 7);
#pragma unroll
                for (int r = 0; r < 4; r++)
                    OutQK[fb + (size_t)r * 8] = f2bf(fmaxf(acc[i][j][r] + bb, 0.f));
            } else {
                const size_t fb = ((((size_t)bh * 32 + (s_ >> 6)) * 4 + (dk >> 4)) * 2
                                   + ((s_ >> 5) & 1)) * 512
                                + (size_t)((((s_ & 31) >> 3) * 16) + (dk & 15)) * 8 + (s_ & 7);
                uint2 pk;
                pk.x = (unsigned)f2bf(fmaxf(acc[i][j][0] + bb, 0.f))
                     | ((unsigned)f2bf(fmaxf(acc[i][j][1] + bb, 0.f)) << 16);
                pk.y = (unsigned)f2bf(fmaxf(acc[i][j][2] + bb, 0.f))
                     | ((unsigned)f2bf(fmaxf(acc[i][j][3] + bb, 0.f)) << 16);
                *(uint2*)&Vo[fb] = pk;
            }
        }
    }
}

// ---------------------------------------------------------------------------
// flash attention, bf16 MFMA. R19 = exact R16 geometry (the proven optimum:
// 512 blocks x 512 thr, 128-key dbuf tiles, permlane P-transpose, ones-MFMA
// l-sum -- every throughput/occupancy/topology lever R10/R11/R13/R14/R15/
// R17/R18 was null or negative; only instruction-deletion ever moved dur)
// + v_cvt_pk_bf16_f32 packing: 16x pk2bf (3 VALU each) -> 16x cvt_pk
// (1 VALU each) per wave-iter = -32 issued VALU (-27% of inner-loop VALU).
// RNE-vs-half-away rounding differs only on exact 0x8000 tails (~2^-16).
// ---------------------------------------------------------------------------
__global__ __launch_bounds__(512, 4) void attn_kernel(
    const unsigned short* __restrict__ Qf,
    const unsigned short* __restrict__ Kf,
    const unsigned short* __restrict__ Vf,
    unsigned short* __restrict__ ctxb)
{
    __shared__ __align__(16) unsigned short KVs[2][16384];  // [buf][K 16KB | V 16KB]
    __shared__ float Lx[4][2][64];                          // [qq][t][lane]

    const int blk = blockIdx.x;                // 0..511
    const int xcd = blk & 7;
    const int j_  = blk >> 3;
    const int bh  = xcd * 4 + (j_ & 3);        // 4 heads per XCD
    const int qt  = j_ >> 2;                   // 0..15: 128-query tile

    const int tid  = threadIdx.x;
    const int wv   = tid >> 6;                 // 0..7
    const int lane = tid & 63;
    const int lq   = lane & 15;
    const int g    = lane >> 4;
    const int qq   = wv >> 1;                  // query quarter: 32 queries
    const int kh   = wv & 1;                   // key half of the 128-key tile

    const int q0 = qt * 128 + qq * 32;

    // ---- Q fragments: 2 query-tiles x 2 k-chunks (32 queries) ----
    bf16x8 qa[2], qb[2];
    const size_t qfB = ((size_t)bh * 128 + (q0 >> 4)) * 1024 + (size_t)lane * 8;
#pragma unroll
    for (int t = 0; t < 2; t++) {
        qa[t] = *(const bf16x8*)&Qf[qfB + (size_t)t * 1024];
        qb[t] = *(const bf16x8*)&Qf[qfB + (size_t)t * 1024 + 512];
    }

    const float C  = 0.18033688011112042f;   // log2(e)/8
    const float MC = 2.8853900817779267f;    // 16*C fixed shift (scores >= 0)

    // all-ones bf16 A-fragment for the l-sum MFMA (1.0 = 0x3F80)
    const short one_bf = (short)0x3F80;
    const bf16x8 ones8 = (bf16x8){one_bf, one_bf, one_bf, one_bf,
                                  one_bf, one_bf, one_bf, one_bf};

    const unsigned short* KtB = &Kf[(size_t)bh * 131072];
    const unsigned short* VtB = &Vf[(size_t)bh * 131072];

    floatx4 accl[2];
    floatx4 acc[2][4];                         // [qtile][dk-tile]
#pragma unroll
    for (int t = 0; t < 2; t++) {
        accl[t] = (floatx4){0.f, 0.f, 0.f, 0.f};
#pragma unroll
        for (int n = 0; n < 4; n++) acc[t][n] = (floatx4){0.f, 0.f, 0.f, 0.f};
    }

    // ---- stage tile 0 into buf 0: wave wv copies K,V chunks 2wv,2wv+1 ----
#pragma unroll
    for (int r = 0; r < 2; r++) {
        const int c = wv * 2 + r;
        gld16(&KtB[(size_t)c * 512 + lane * 8], &KVs[0][c * 512]);
        gld16(&VtB[(size_t)c * 512 + lane * 8], &KVs[0][8192 + c * 512]);
    }
    __syncthreads();   // compiler drains vmcnt before s_barrier

    for (int jt = 0; jt < SEQ / 128; jt++) {
        const int buf = jt & 1;

        // ---- prefetch next 128-key tile into the other buffer ----
        const int jn = (jt + 1) & (SEQ / 128 - 1);
        const unsigned short* ktn = &KtB[(size_t)jn * 8192];
        const unsigned short* vtn = &VtB[(size_t)jn * 8192];
#pragma unroll
        for (int r = 0; r < 2; r++) {
            const int c = wv * 2 + r;
            gld16(&ktn[(size_t)c * 512 + lane * 8], &KVs[buf ^ 1][c * 512]);
            gld16(&vtn[(size_t)c * 512 + lane * 8], &KVs[buf ^ 1][8192 + c * 512]);
        }

        const unsigned short* kb = &KVs[buf][0];
        const unsigned short* vb = &KVs[buf][8192];

        // ---- two 32-key sub-steps over this wave's 64-key half ----
#pragma unroll
        for (int s = 0; s < 2; s++) {
            const int kg = 4 * kh + 2 * s;     // first of two 16-key groups
            bf16x8 a0 = *(const bf16x8*)&kb[(kg + 0) * 1024 + lane * 8];
            bf16x8 a1 = *(const bf16x8*)&kb[(kg + 0) * 1024 + 512 + lane * 8];
            bf16x8 a2 = *(const bf16x8*)&kb[(kg + 1) * 1024 + lane * 8];
            bf16x8 a3 = *(const bf16x8*)&kb[(kg + 1) * 1024 + 512 + lane * 8];
            bf16x8 vr[4];
#pragma unroll
            for (int n = 0; n < 4; n++)
                vr[n] = *(const bf16x8*)&vb[(kh * 4 + n) * 1024 + s * 512 + lane * 8];

#pragma unroll
            for (int t = 0; t < 2; t++) {
                floatx4 s0 = (floatx4){0.f, 0.f, 0.f, 0.f};
                floatx4 s1 = (floatx4){0.f, 0.f, 0.f, 0.f};
                s0 = __builtin_amdgcn_mfma_f32_16x16x32_bf16(a0, qa[t], s0, 0, 0, 0);
                s0 = __builtin_amdgcn_mfma_f32_16x16x32_bf16(a1, qb[t], s0, 0, 0, 0);
                s1 = __builtin_amdgcn_mfma_f32_16x16x32_bf16(a2, qa[t], s1, 0, 0, 0);
                s1 = __builtin_amdgcn_mfma_f32_16x16x32_bf16(a3, qb[t], s1, 0, 0, 0);

                float p00 = __builtin_amdgcn_exp2f(fmaf(s0[0], C, -MC));
                float p01 = __builtin_amdgcn_exp2f(fmaf(s0[1], C, -MC));
                float p02 = __builtin_amdgcn_exp2f(fmaf(s0[2], C, -MC));
                float p03 = __builtin_amdgcn_exp2f(fmaf(s0[3], C, -MC));
                unsigned d0 = cvtpk(p00, p01);
                unsigned d1 = cvtpk(p02, p03);

                float p10 = __builtin_amdgcn_exp2f(fmaf(s1[0], C, -MC));
                float p11 = __builtin_amdgcn_exp2f(fmaf(s1[1], C, -MC));
                float p12 = __builtin_amdgcn_exp2f(fmaf(s1[2], C, -MC));
                float p13 = __builtin_amdgcn_exp2f(fmaf(s1[3], C, -MC));
                unsigned d2 = cvtpk(p10, p11);
                unsigned d3 = cvtpk(p12, p13);

                // in-register transpose: lane=(p1,g1'), reg=(g0',p0)
                uintx2 r02 = __builtin_amdgcn_permlane32_swap(d0, d2, false, false);
                uintx2 r13 = __builtin_amdgcn_permlane32_swap(d1, d3, false, false);
                uintx2 f02 = __builtin_amdgcn_permlane16_swap(r02.x, r02.y, false, false);
                uintx2 f13 = __builtin_amdgcn_permlane16_swap(r13.x, r13.y, false, false);

                union { unsigned u[4]; bf16x8 v; } pbu;
                pbu.u[0] = f02.x;   // keys 8g+0,1
                pbu.u[1] = f13.x;   // keys 8g+2,3
                pbu.u[2] = f02.y;   // keys 8g+4,5
                pbu.u[3] = f13.y;   // keys 8g+6,7

                // softmax denominator on the MFMA pipe: D[*,q] = sum_k P[k,q]
                accl[t] = __builtin_amdgcn_mfma_f32_16x16x32_bf16(ones8, pbu.v, accl[t], 0, 0, 0);

#pragma unroll
                for (int n = 0; n < 4; n++)
                    acc[t][n] = __builtin_amdgcn_mfma_f32_16x16x32_bf16(vr[n], pbu.v, acc[t][n], 0, 0, 0);
            }
        }

        __syncthreads();   // staging of buf^1 complete + all waves done with buf
    }

    // ---- cross-wave partner reduction: kh=1 -> LDS (dead KV buffer) -> kh=0 ----
    float* red = (float*)&KVs[0][0] + (size_t)qq * 2048;   // 8KB region per qq
    if (kh == 1) {
#pragma unroll
        for (int t = 0; t < 2; t++) {
            Lx[qq][t][lane] = accl[t][0];
#pragma unroll
            for (int n = 0; n < 4; n++)
                *(floatx4*)&red[(t * 4 + n) * 256 + lane * 4] = acc[t][n];
        }
    }
    __syncthreads();
    if (kh == 0) {
        const int b_ = bh >> 4, h_ = bh & 15;
#pragma unroll
        for (int t = 0; t < 2; t++) {
            const float lt = accl[t][0] + Lx[qq][t][lane];
            const float li = 1.f / lt;
#pragma unroll
            for (int n = 0; n < 4; n++) {
                floatx4 a = acc[t][n];
                floatx4 b = *(const floatx4*)&red[(t * 4 + n) * 256 + lane * 4];
                uint2 pk;
                pk.x = pk2bf((a[0] + b[0]) * li, (a[1] + b[1]) * li);
                pk.y = pk2bf((a[2] + b[2]) * li, (a[3] + b[3]) * li);
                *(uint2*)&ctxb[((size_t)(b_ * SEQ) + q0 + t * 16 + lq) * D_MODEL
                               + h_ * DK + n * 16 + g * 4] = pk;
            }
        }
    }
}

// ---------------------------------------------------------------------------
// gemm_o (R13 64x64 retile, kept)
// ---------------------------------------------------------------------------
__global__ __launch_bounds__(256) void gemm_o(
    const unsigned short* __restrict__ Abf,
    const unsigned short* __restrict__ Bp,
    const float* __restrict__ bo,
    float* __restrict__ out)
{
    __shared__ __align__(16) unsigned short As[64 * 32];
    __shared__ __align__(16) unsigned short Bs[64 * 32];

    const int tid  = threadIdx.x;
    const int wv   = tid >> 6, lane = tid & 63;
    const int bid  = blockIdx.x;
    const int swz  = (bid & 7) * 128 + (bid >> 3);
    const int m0   = (swz & 63) * 64;
    const int n0   = (swz >> 6) * 64;
    const int lq   = lane & 15, g = lane >> 4;
    const int wm   = (wv >> 1) * 32;
    const int wn   = (wv & 1) * 32;
    const int srow = lane >> 2;
    const int sseg = (lane & 3) * 8;

    floatx4 acc[2][2];
#pragma unroll
    for (int i = 0; i < 2; i++)
#pragma unroll
        for (int j = 0; j < 2; j++) acc[i][j] = (floatx4){0.f, 0.f, 0.f, 0.f};

    for (int k0 = 0; k0 < 1024; k0 += 32) {
        const int row = wv * 16 + srow;
        gld16(&Abf[(size_t)(m0 + row) * 1024 + k0 + sseg], &As[wv * 512]);
        gld16(&Bp [(size_t)(n0 + row) * 1024 + k0 + sseg], &Bs[wv * 512]);
        __syncthreads();
        bf16x8 af[2], bfv[2];
#pragma unroll
        for (int i = 0; i < 2; i++)
            af[i] = *(const bf16x8*)&As[(wm + i * 16 + lq) * 32 + g * 8];
#pragma unroll
        for (int j = 0; j < 2; j++)
            bfv[j] = *(const bf16x8*)&Bs[(wn + j * 16 + lq) * 32 + g * 8];
#pragma unroll
        for (int i = 0; i < 2; i++)
#pragma unroll
            for (int j = 0; j < 2; j++)
                acc[i][j] = __builtin_amdgcn_mfma_f32_16x16x32_bf16(af[i], bfv[j], acc[i][j], 0, 0, 0);
        __syncthreads();
    }

#pragma unroll
    for (int j = 0; j < 2; j++) {
        const int n  = n0 + wn + j * 16 + lq;
        const float bb = bo[n];
#pragma unroll
        for (int i = 0; i < 2; i++) {
#pragma unroll
            for (int r = 0; r < 4; r++) {
                const int m = m0 + wm + i * 16 + g * 4 + r;
                out[(size_t)m * 1024 + n] = fmaxf(acc[i][j][r] + bb, 0.f);
            }
        }
    }
}

extern "C" void kernel_launch(void* const* d_in, const int* in_sizes, int n_in,
                              void* d_out, int out_size, void* d_ws, size_t ws_size,
                              hipStream_t stream) {
    const float* x  = (const float*)d_in[0];
    const float* Wq = (const float*)d_in[1];
    const float* bq = (const float*)d_in[2];
    const float* Wk = (const float*)d_in[3];
    const float* bk = (const float*)d_in[4];
    const float* Wv = (const float*)d_in[5];
    const float* bv = (const float*)d_in[6];
    const float* Wo = (const float*)d_in[7];
    const float* bo = (const float*)d_in[8];
    float* out = (float*)d_out;

    const size_t perE = (size_t)NB * NH * SEQ * DK;      // 4,194,304
    unsigned short* xbf  = (unsigned short*)d_ws;        // 8 MB
    unsigned short* Bqkv = xbf  + (size_t)4096 * 1024;   // 6 MB
    unsigned short* Bo   = Bqkv + (size_t)3072 * 1024;   // 2 MB
    unsigned short* Qfr  = Bo   + (size_t)1024 * 1024;   // 8 MB (fragment layout)
    unsigned short* Kfr  = Qfr + perE;                   // 8 MB
    unsigned short* Vfr  = Kfr + perE;                   // 8 MB
    unsigned short* Cbf  = Vfr + perE;                   // 8 MB

    prep<<<2048, 256, 0, stream>>>(x, xbf, Wq, Wk, Wv, Wo, Bqkv, Bo);
    gemm_qkv<<<dim3(32, 24), 256, 0, stream>>>(xbf, Bqkv, bq, bk, bv, Qfr, Kfr, Vfr);
    attn_kernel<<<512, 512, 0, stream>>>(Qfr, Kfr, Vfr, Cbf);
    gemm_o<<<1024, 256, 0, stream>>>(Cbf, Bo, bo, out);
}

// Round 11
// 178.151 us; speedup vs baseline: 1.0685x; 1.0197x over previous
//
#include <hip/hip_runtime.h>
#include <cstddef>

#define D_MODEL 1024
#define DK 64
#define NH 16
#define NB 2
#define SEQ 2048

typedef __attribute__((ext_vector_type(8))) short bf16x8;
typedef __attribute__((ext_vector_type(4))) float floatx4;
typedef __attribute__((ext_vector_type(2))) unsigned uintx2;

static __device__ __forceinline__ unsigned short f2bf(float f) {
    union { float f; unsigned u; } v; v.f = f;
    unsigned r = (v.u + 0x7fffu + ((v.u >> 16) & 1u)) >> 16;
    return (unsigned short)r;
}

// pack two floats' bf16 (round-half-away) into one dword
static __device__ __forceinline__ unsigned pk2bf(float lo, float hi) {
    unsigned ua = __float_as_uint(lo) + 0x8000u;
    unsigned ub = __float_as_uint(hi) + 0x8000u;
    return __builtin_amdgcn_perm(ub, ua, 0x07060302u);
}

// packed f32x2 -> bf16x2 in ONE VALU op (RNE rounding)
static __device__ __forceinline__ unsigned cvtpk(float lo, float hi) {
    unsigned r;
    asm("v_cvt_pk_bf16_f32 %0, %1, %2" : "=v"(r) : "v"(lo), "v"(hi));
    return r;
}

static __device__ __forceinline__ void gld16(const unsigned short* g, unsigned short* l) {
    __builtin_amdgcn_global_load_lds(
        (const __attribute__((address_space(1))) unsigned int*)g,
        (__attribute__((address_space(3))) unsigned int*)l, 16, 0, 0);
}

// ---------------------------------------------------------------------------
// prep: fused convert_x (blocks 0..1023) + pack_w (blocks 1024..2047).
// ---------------------------------------------------------------------------
__global__ __launch_bounds__(256) void prep(
    const float* __restrict__ x, unsigned short* __restrict__ xb,
    const float* __restrict__ Wq, const float* __restrict__ Wk,
    const float* __restrict__ Wv, const float* __restrict__ Wo,
    unsigned short* __restrict__ Bqkv, unsigned short* __restrict__ Bo)
{
    __shared__ float T[64][65];
    const int tid = threadIdx.x;

    if (blockIdx.x < 1024) {
        const size_t i = ((size_t)blockIdx.x * 256 + tid) * 16;
#pragma unroll
        for (int c = 0; c < 16; c += 4) {
            float4 v = *(const float4*)&x[i + c];
            uint2 pk;
            pk.x = (unsigned)f2bf(v.x) | ((unsigned)f2bf(v.y) << 16);
            pk.y = (unsigned)f2bf(v.z) | ((unsigned)f2bf(v.w) << 16);
            *(uint2*)&xb[i + c] = pk;
        }
        return;
    }

    const int t   = blockIdx.x - 1024;
    const int rr   = tid >> 2;
    const int cseg = (tid & 3) * 16;

    const float* src;
    unsigned short* dst;
    if (t < 768) {
        const int proj = t / 256, rem = t % 256;
        const int h = rem >> 4, d0 = (rem & 15) * 64;
        const float* W = proj == 0 ? Wq : (proj == 1 ? Wk : Wv);
        src = W + ((size_t)h * 1024 + d0) * 64;
#pragma unroll
        for (int c = 0; c < 16; c += 4) {
            float4 v = *(const float4*)&src[(size_t)rr * 64 + cseg + c];
            T[rr][cseg + c + 0] = v.x; T[rr][cseg + c + 1] = v.y;
            T[rr][cseg + c + 2] = v.z; T[rr][cseg + c + 3] = v.w;
        }
        __syncthreads();
        dst = &Bqkv[((size_t)proj * 1024 + h * 64 + rr) * 1024 + d0 + cseg];
    } else {
        const int t2 = t - 768;
        const int k0 = (t2 >> 4) * 64, nb0 = (t2 & 15) * 64;
#pragma unroll
        for (int c = 0; c < 16; c += 4) {
            float4 v = *(const float4*)&Wo[(size_t)(k0 + rr) * 1024 + nb0 + cseg + c];
            T[rr][cseg + c + 0] = v.x; T[rr][cseg + c + 1] = v.y;
            T[rr][cseg + c + 2] = v.z; T[rr][cseg + c + 3] = v.w;
        }
        __syncthreads();
        dst = &Bo[(size_t)(nb0 + rr) * 1024 + k0 + cseg];
    }
    unsigned int w[8];
#pragma unroll
    for (int ii = 0; ii < 8; ii++) {
        unsigned short lo = f2bf(T[cseg + ii * 2 + 0][rr]);
        unsigned short hi = f2bf(T[cseg + ii * 2 + 1][rr]);
        w[ii] = (unsigned)lo | ((unsigned)hi << 16);
    }
    *(uint4*)(dst + 0) = make_uint4(w[0], w[1], w[2], w[3]);
    *(uint4*)(dst + 8) = make_uint4(w[4], w[5], w[6], w[7]);
}

// ---------------------------------------------------------------------------
// gemm_qkv (R14/BK=32). R20: Q outputs pre-scaled by C = log2(e)/8 so the
// attn QK MFMA emits s*C directly (relu(x)*C == relu(x*C), C>0; cold
// epilogue, one v_mul per element, proj==0 only -- K uses qs=1.0 exactly).
// ---------------------------------------------------------------------------
__global__ __launch_bounds__(256) void gemm_qkv(
    const unsigned short* __restrict__ Abf,
    const unsigned short* __restrict__ Bp,
    const float* __restrict__ bq, const float* __restrict__ bk,
    const float* __restrict__ bv,
    unsigned short* __restrict__ Qo, unsigned short* __restrict__ Ko,
    unsigned short* __restrict__ Vo)
{
    __shared__ __align__(16) unsigned short As[128 * 32];
    __shared__ __align__(16) unsigned short Bs[128 * 32];

    const int tid  = threadIdx.x;
    const int wv   = tid >> 6, lane = tid & 63;
    const int m0   = blockIdx.x * 128;
    const int n0   = blockIdx.y * 128;
    const int lq   = lane & 15, g = lane >> 4;
    const int wm   = (wv >> 1) * 64;
    const int wn   = (wv & 1) * 64;
    const int srow = lane >> 2;
    const int sseg = (lane & 3) * 8;

    floatx4 acc[4][4];
#pragma unroll
    for (int i = 0; i < 4; i++)
#pragma unroll
        for (int j = 0; j < 4; j++) acc[i][j] = (floatx4){0.f, 0.f, 0.f, 0.f};

    for (int k0 = 0; k0 < 1024; k0 += 32) {
#pragma unroll
        for (int r = 0; r < 2; r++) {
            const int chunk = wv * 2 + r;
            const int row   = chunk * 16 + srow;
            gld16(&Abf[(size_t)(m0 + row) * 1024 + k0 + sseg], &As[chunk * 512]);
            gld16(&Bp [(size_t)(n0 + row) * 1024 + k0 + sseg], &Bs[chunk * 512]);
        }
        __syncthreads();
        bf16x8 af[4], bfv[4];
#pragma unroll
        for (int i = 0; i < 4; i++)
            af[i] = *(const bf16x8*)&As[(wm + i * 16 + lq) * 32 + g * 8];
#pragma unroll
        for (int j = 0; j < 4; j++)
            bfv[j] = *(const bf16x8*)&Bs[(wn + j * 16 + lq) * 32 + g * 8];
#pragma unroll
        for (int i = 0; i < 4; i++)
#pragma unroll
            for (int j = 0; j < 4; j++)
                acc[i][j] = __builtin_amdgcn_mfma_f32_16x16x32_bf16(af[i], bfv[j], acc[i][j], 0, 0, 0);
        __syncthreads();
    }

    const int proj = n0 >> 10;
    const float* bias = proj == 0 ? bq : (proj == 1 ? bk : bv);
    unsigned short* OutQK = proj == 0 ? Qo : Ko;
    const float qs = proj == 0 ? 0.18033688011112042f : 1.0f;  // log2(e)/8

#pragma unroll
    for (int j = 0; j < 4; j++) {
        const int n  = n0 + wn + j * 16 + lq;
        const int nn = n & 1023;
        const int h  = nn >> 6, dk = nn & 63;
        const float bb = bias[nn];
#pragma unroll
        for (int i = 0; i < 4; i++) {
            const int mbase = m0 + wm + i * 16 + g * 4;
            const int b_ = mbase >> 11;
            const int s_ = mbase & (SEQ - 1);
            const int bh = b_ * NH + h;
            if (proj < 2) {
                const size_t fb = (((size_t)bh * 128 + (s_ >> 4)) * 2 + (dk >> 5)) * 512
                                + (size_t)((((dk & 31) >> 3) * 16) + (s_ & 15)) * 8 + (dk & 7);
#pragma unroll
                for (int r = 0; r < 4; r++)
                    OutQK[fb + (size_t)r * 8] = f2bf(fmaxf(acc[i][j][r] + bb, 0.f) * qs);
            } else {
                const size_t fb = ((((size_t)bh * 32 + (s_ >> 6)) * 4 + (dk >> 4)) * 2
                                   + ((s_ >> 5) & 1)) * 512
                                + (size_t)((((s_ & 31) >> 3) * 16) + (dk & 15)) * 8 + (s_ & 7);
                uint2 pk;
                pk.x = (unsigned)f2bf(fmaxf(acc[i][j][0] + bb, 0.f))
                     | ((unsigned)f2bf(fmaxf(acc[i][j][1] + bb, 0.f)) << 16);
                pk.y = (unsigned)f2bf(fmaxf(acc[i][j][2] + bb, 0.f))
                     | ((unsigned)f2bf(fmaxf(acc[i][j][3] + bb, 0.f)) << 16);
                *(uint2*)&Vo[fb] = pk;
            }
        }
    }
}

// ---------------------------------------------------------------------------
// flash attention, bf16 MFMA. R20 = R19 + fmaf layer deleted:
// Q pre-scaled by C in gemm_qkv -> QK MFMA emits s*C; the fixed shift MC
// folds into normalization (p' = 2^MC * p uniformly scales numerator AND
// denominator -> cancels in (sum p*v)/(sum p); values 7.4x larger, far from
// bf16/f32 range limits, relative precision unchanged). Inner loop is now
// exp2 DIRECTLY on MFMA outputs: -32 VALU/iter/wave (-25% of remaining
// issued VALU) and one fewer op on the MFMA->exp2 chain. Same lever class
// as R12/R16/R19 (3/3 hit rate; every other lever class was null/negative).
// ---------------------------------------------------------------------------
__global__ __launch_bounds__(512, 4) void attn_kernel(
    const unsigned short* __restrict__ Qf,
    const unsigned short* __restrict__ Kf,
    const unsigned short* __restrict__ Vf,
    unsigned short* __restrict__ ctxb)
{
    __shared__ __align__(16) unsigned short KVs[2][16384];  // [buf][K 16KB | V 16KB]
    __shared__ float Lx[4][2][64];                          // [qq][t][lane]

    const int blk = blockIdx.x;                // 0..511
    const int xcd = blk & 7;
    const int j_  = blk >> 3;
    const int bh  = xcd * 4 + (j_ & 3);        // 4 heads per XCD
    const int qt  = j_ >> 2;                   // 0..15: 128-query tile

    const int tid  = threadIdx.x;
    const int wv   = tid >> 6;                 // 0..7
    const int lane = tid & 63;
    const int lq   = lane & 15;
    const int g    = lane >> 4;
    const int qq   = wv >> 1;                  // query quarter: 32 queries
    const int kh   = wv & 1;                   // key half of the 128-key tile

    const int q0 = qt * 128 + qq * 32;

    // ---- Q fragments: 2 query-tiles x 2 k-chunks (32 queries) ----
    bf16x8 qa[2], qb[2];
    const size_t qfB = ((size_t)bh * 128 + (q0 >> 4)) * 1024 + (size_t)lane * 8;
#pragma unroll
    for (int t = 0; t < 2; t++) {
        qa[t] = *(const bf16x8*)&Qf[qfB + (size_t)t * 1024];
        qb[t] = *(const bf16x8*)&Qf[qfB + (size_t)t * 1024 + 512];
    }

    // all-ones bf16 A-fragment for the l-sum MFMA (1.0 = 0x3F80)
    const short one_bf = (short)0x3F80;
    const bf16x8 ones8 = (bf16x8){one_bf, one_bf, one_bf, one_bf,
                                  one_bf, one_bf, one_bf, one_bf};

    const unsigned short* KtB = &Kf[(size_t)bh * 131072];
    const unsigned short* VtB = &Vf[(size_t)bh * 131072];

    floatx4 accl[2];
    floatx4 acc[2][4];                         // [qtile][dk-tile]
#pragma unroll
    for (int t = 0; t < 2; t++) {
        accl[t] = (floatx4){0.f, 0.f, 0.f, 0.f};
#pragma unroll
        for (int n = 0; n < 4; n++) acc[t][n] = (floatx4){0.f, 0.f, 0.f, 0.f};
    }

    // ---- stage tile 0 into buf 0: wave wv copies K,V chunks 2wv,2wv+1 ----
#pragma unroll
    for (int r = 0; r < 2; r++) {
        const int c = wv * 2 + r;
        gld16(&KtB[(size_t)c * 512 + lane * 8], &KVs[0][c * 512]);
        gld16(&VtB[(size_t)c * 512 + lane * 8], &KVs[0][8192 + c * 512]);
    }
    __syncthreads();   // compiler drains vmcnt before s_barrier

    for (int jt = 0; jt < SEQ / 128; jt++) {
        const int buf = jt & 1;

        // ---- prefetch next 128-key tile into the other buffer ----
        const int jn = (jt + 1) & (SEQ / 128 - 1);
        const unsigned short* ktn = &KtB[(size_t)jn * 8192];
        const unsigned short* vtn = &VtB[(size_t)jn * 8192];
#pragma unroll
        for (int r = 0; r < 2; r++) {
            const int c = wv * 2 + r;
            gld16(&ktn[(size_t)c * 512 + lane * 8], &KVs[buf ^ 1][c * 512]);
            gld16(&vtn[(size_t)c * 512 + lane * 8], &KVs[buf ^ 1][8192 + c * 512]);
        }

        const unsigned short* kb = &KVs[buf][0];
        const unsigned short* vb = &KVs[buf][8192];

        // ---- two 32-key sub-steps over this wave's 64-key half ----
#pragma unroll
        for (int s = 0; s < 2; s++) {
            const int kg = 4 * kh + 2 * s;     // first of two 16-key groups
            bf16x8 a0 = *(const bf16x8*)&kb[(kg + 0) * 1024 + lane * 8];
            bf16x8 a1 = *(const bf16x8*)&kb[(kg + 0) * 1024 + 512 + lane * 8];
            bf16x8 a2 = *(const bf16x8*)&kb[(kg + 1) * 1024 + lane * 8];
            bf16x8 a3 = *(const bf16x8*)&kb[(kg + 1) * 1024 + 512 + lane * 8];
            bf16x8 vr[4];
#pragma unroll
            for (int n = 0; n < 4; n++)
                vr[n] = *(const bf16x8*)&vb[(kh * 4 + n) * 1024 + s * 512 + lane * 8];

#pragma unroll
            for (int t = 0; t < 2; t++) {
                floatx4 s0 = (floatx4){0.f, 0.f, 0.f, 0.f};
                floatx4 s1 = (floatx4){0.f, 0.f, 0.f, 0.f};
                s0 = __builtin_amdgcn_mfma_f32_16x16x32_bf16(a0, qa[t], s0, 0, 0, 0);
                s0 = __builtin_amdgcn_mfma_f32_16x16x32_bf16(a1, qb[t], s0, 0, 0, 0);
                s1 = __builtin_amdgcn_mfma_f32_16x16x32_bf16(a2, qa[t], s1, 0, 0, 0);
                s1 = __builtin_amdgcn_mfma_f32_16x16x32_bf16(a3, qb[t], s1, 0, 0, 0);

                // p = exp2(s) directly: C folded into Q, MC folded into 1/l
                float p00 = __builtin_amdgcn_exp2f(s0[0]);
                float p01 = __builtin_amdgcn_exp2f(s0[1]);
                float p02 = __builtin_amdgcn_exp2f(s0[2]);
                float p03 = __builtin_amdgcn_exp2f(s0[3]);
                unsigned d0 = cvtpk(p00, p01);
                unsigned d1 = cvtpk(p02, p03);

                float p10 = __builtin_amdgcn_exp2f(s1[0]);
                float p11 = __builtin_amdgcn_exp2f(s1[1]);
                float p12 = __builtin_amdgcn_exp2f(s1[2]);
                float p13 = __builtin_amdgcn_exp2f(s1[3]);
                unsigned d2 = cvtpk(p10, p11);
                unsigned d3 = cvtpk(p12, p13);

                // in-register transpose: lane=(p1,g1'), reg=(g0',p0)
                uintx2 r02 = __builtin_amdgcn_permlane32_swap(d0, d2, false, false);
                uintx2 r13 = __builtin_amdgcn_permlane32_swap(d1, d3, false, false);
                uintx2 f02 = __builtin_amdgcn_permlane16_swap(r02.x, r02.y, false, false);
                uintx2 f13 = __builtin_amdgcn_permlane16_swap(r13.x, r13.y, false, false);

                union { unsigned u[4]; bf16x8 v; } pbu;
                pbu.u[0] = f02.x;   // keys 8g+0,1
                pbu.u[1] = f13.x;   // keys 8g+2,3
                pbu.u[2] = f02.y;   // keys 8g+4,5
                pbu.u[3] = f13.y;   // keys 8g+6,7

                // softmax denominator on the MFMA pipe: D[*,q] = sum_k P[k,q]
                accl[t] = __builtin_amdgcn_mfma_f32_16x16x32_bf16(ones8, pbu.v, accl[t], 0, 0, 0);

#pragma unroll
                for (int n = 0; n < 4; n++)
                    acc[t][n] = __builtin_amdgcn_mfma_f32_16x16x32_bf16(vr[n], pbu.v, acc[t][n], 0, 0, 0);
            }
        }

        __syncthreads();   // staging of buf^1 complete + all waves done with buf
    }

    // ---- cross-wave partner reduction: kh=1 -> LDS (dead KV buffer) -> kh=0 ----
    float* red = (float*)&KVs[0][0] + (size_t)qq * 2048;   // 8KB region per qq
    if (kh == 1) {
#pragma unroll
        for (int t = 0; t < 2; t++) {
            Lx[qq][t][lane] = accl[t][0];
#pragma unroll
            for (int n = 0; n < 4; n++)
                *(floatx4*)&red[(t * 4 + n) * 256 + lane * 4] = acc[t][n];
        }
    }
    __syncthreads();
    if (kh == 0) {
        const int b_ = bh >> 4, h_ = bh & 15;
#pragma unroll
        for (int t = 0; t < 2; t++) {
            const float lt = accl[t][0] + Lx[qq][t][lane];
            const float li = 1.f / lt;
#pragma unroll
            for (int n = 0; n < 4; n++) {
                floatx4 a = acc[t][n];
                floatx4 b = *(const floatx4*)&red[(t * 4 + n) * 256 + lane * 4];
                uint2 pk;
                pk.x = pk2bf((a[0] + b[0]) * li, (a[1] + b[1]) * li);
                pk.y = pk2bf((a[2] + b[2]) * li, (a[3] + b[3]) * li);
                *(uint2*)&ctxb[((size_t)(b_ * SEQ) + q0 + t * 16 + lq) * D_MODEL
                               + h_ * DK + n * 16 + g * 4] = pk;
            }
        }
    }
}

// ---------------------------------------------------------------------------
// gemm_o (R13 64x64 retile, kept)
// ---------------------------------------------------------------------------
__global__ __launch_bounds__(256) void gemm_o(
    const unsigned short* __restrict__ Abf,
    const unsigned short* __restrict__ Bp,
    const float* __restrict__ bo,
    float* __restrict__ out)
{
    __shared__ __align__(16) unsigned short As[64 * 32];
    __shared__ __align__(16) unsigned short Bs[64 * 32];

    const int tid  = threadIdx.x;
    const int wv   = tid >> 6, lane = tid & 63;
    const int bid  = blockIdx.x;
    const int swz  = (bid & 7) * 128 + (bid >> 3);
    const int m0   = (swz & 63) * 64;
    const int n0   = (swz >> 6) * 64;
    const int lq   = lane & 15, g = lane >> 4;
    const int wm   = (wv >> 1) * 32;
    const int wn   = (wv & 1) * 32;
    const int srow = lane >> 2;
    const int sseg = (lane & 3) * 8;

    floatx4 acc[2][2];
#pragma unroll
    for (int i = 0; i < 2; i++)
#pragma unroll
        for (int j = 0; j < 2; j++) acc[i][j] = (floatx4){0.f, 0.f, 0.f, 0.f};

    for (int k0 = 0; k0 < 1024; k0 += 32) {
        const int row = wv * 16 + srow;
        gld16(&Abf[(size_t)(m0 + row) * 1024 + k0 + sseg], &As[wv * 512]);
        gld16(&Bp [(size_t)(n0 + row) * 1024 + k0 + sseg], &Bs[wv * 512]);
        __syncthreads();
        bf16x8 af[2], bfv[2];
#pragma unroll
        for (int i = 0; i < 2; i++)
            af[i] = *(const bf16x8*)&As[(wm + i * 16 + lq) * 32 + g * 8];
#pragma unroll
        for (int j = 0; j < 2; j++)
            bfv[j] = *(const bf16x8*)&Bs[(wn + j * 16 + lq) * 32 + g * 8];
#pragma unroll
        for (int i = 0; i < 2; i++)
#pragma unroll
            for (int j = 0; j < 2; j++)
                acc[i][j] = __builtin_amdgcn_mfma_f32_16x16x32_bf16(af[i], bfv[j], acc[i][j], 0, 0, 0);
        __syncthreads();
    }

#pragma unroll
    for (int j = 0; j < 2; j++) {
        const int n  = n0 + wn + j * 16 + lq;
        const float bb = bo[n];
#pragma unroll
        for (int i = 0; i < 2; i++) {
#pragma unroll
            for (int r = 0; r < 4; r++) {
                const int m = m0 + wm + i * 16 + g * 4 + r;
                out[(size_t)m * 1024 + n] = fmaxf(acc[i][j][r] + bb, 0.f);
            }
        }
    }
}

extern "C" void kernel_launch(void* const* d_in, const int* in_sizes, int n_in,
                              void* d_out, int out_size, void* d_ws, size_t ws_size,
                              hipStream_t stream) {
    const float* x  = (const float*)d_in[0];
    const float* Wq = (const float*)d_in[1];
    const float* bq = (const float*)d_in[2];
    const float* Wk = (const float*)d_in[3];
    const float* bk = (const float*)d_in[4];
    const float* Wv = (const float*)d_in[5];
    const float* bv = (const float*)d_in[6];
    const float* Wo = (const float*)d_in[7];
    const float* bo = (const float*)d_in[8];
    float* out = (float*)d_out;

    const size_t perE = (size_t)NB * NH * SEQ * DK;      // 4,194,304
    unsigned short* xbf  = (unsigned short*)d_ws;        // 8 MB
    unsigned short* Bqkv = xbf  + (size_t)4096 * 1024;   // 6 MB
    unsigned short* Bo   = Bqkv + (size_t)3072 * 1024;   // 2 MB
    unsigned short* Qfr  = Bo   + (size_t)1024 * 1024;   // 8 MB (fragment layout)
    unsigned short* Kfr  = Qfr + perE;                   // 8 MB
    unsigned short* Vfr  = Kfr + perE;                   // 8 MB
    unsigned short* Cbf  = Vfr + perE;                   // 8 MB

    prep<<<2048, 256, 0, stream>>>(x, xbf, Wq, Wk, Wv, Wo, Bqkv, Bo);
    gemm_qkv<<<dim3(32, 24), 256, 0, stream>>>(xbf, Bqkv, bq, bk, bv, Qfr, Kfr, Vfr);
    attn_kernel<<<512, 512, 0, stream>>>(Qfr, Kfr, Vfr, Cbf);
    gemm_o<<<1024, 256, 0, stream>>>(Cbf, Bo, bo, out);
}